// Round 6
// baseline (839.736 us; speedup 1.0000x reference)
//
#include <hip/hip_runtime.h>
#include <cstdint>

#define NLEV 16
#define TMASK ((1u << 19) - 1u)

typedef float f4v __attribute__((ext_vector_type(4)));
typedef float f2v __attribute__((ext_vector_type(2)));
typedef uint32_t u2v __attribute__((ext_vector_type(2)));

// res[l] = ceil(16 * 1.2^l) in float64 (matches numpy)
__constant__ int c_res[NLEV] = {16, 20, 24, 28, 34, 40, 48, 58, 69, 83,
                                100, 119, 143, 172, 206, 247};

__device__ __forceinline__ float bf_lo(uint32_t e) { return __uint_as_float(e << 16); }
__device__ __forceinline__ float bf_hi(uint32_t e) { return __uint_as_float(e & 0xFFFF0000u); }
__device__ __forceinline__ uint32_t rne16(float f) {
    uint32_t u = __float_as_uint(f);
    return (u + 0x7fffu + ((u >> 16) & 1u)) >> 16;
}

// ---- K-1: pack fp32 float2 entries -> one dword (2 x bf16, RNE) ----------
__global__ __launch_bounds__(256) void conv_kernel(
    const f4v* __restrict__ src_s, const f4v* __restrict__ src_t,
    u2v* __restrict__ dst_s, u2v* __restrict__ dst_t, int half)
{
    int i = blockIdx.x * 256 + threadIdx.x;           // one f4 = 2 entries
    const f4v* src = (i < half) ? src_s : src_t;
    u2v* dst = (i < half) ? dst_s : dst_t;
    int j = (i < half) ? i : i - half;
    if (j < half) {
        f4v v = __builtin_nontemporal_load(src + j);
        u2v o;
        o.x = rne16(v.x) | (rne16(v.y) << 16);
        o.y = rne16(v.z) | (rne16(v.w) << 16);
        __builtin_nontemporal_store(o, dst + j);
    }
}

// ---- K0: per-point  one_m = 1 - sigmoid(table_m[nearest]) ----------------
__global__ __launch_bounds__(256) void m_kernel(
    const float* __restrict__ x, const float* __restrict__ tab_m,
    float* __restrict__ one_m, int N)
{
    int n = blockIdx.x * 256 + threadIdx.x;
    if (n >= N) return;
    f4v xv = __builtin_nontemporal_load((const f4v*)x + n);
    float q0 = fminf(fmaxf(rintf(xv.x * 127.0f), 0.0f), 127.0f);
    float q1 = fminf(fmaxf(rintf(xv.y * 127.0f), 0.0f), 127.0f);
    float q2 = fminf(fmaxf(rintf(xv.z * 127.0f), 0.0f), 127.0f);
    uint32_t idx = (uint32_t)q0 + ((uint32_t)q1 << 7) + ((uint32_t)q2 << 14);
    float v = tab_m[idx];
    float m = 1.0f / (1.0f + expf(-v));
    __builtin_nontemporal_store(1.0f - m, one_m + n);
}

// ---- K1: FUSED S+T pass, ONE point per thread, max-occupancy. ------------
// Session ladder (profiled enc, gather-rate lines/cyc/CU):
//   30% occ -> 490us @0.40 | 60% occ (lb 256,6) -> 420us @0.50
// Register pool is the invariant; VGPR_Count settled at 40, so 8 waves/SIMD
// (32/CU, 100% occupancy) fits under the 64-VGPR cap with headroom.
// This round: __launch_bounds__(256,8) -- one-token A/B on the concurrency
// theory. If occupancy rises but time stays ~420, the per-CU outstanding-
// miss cap is confirmed and the next lever is request-count reduction.
__global__ __launch_bounds__(256, 8) void enc_fused(
    const float* __restrict__ x,
    const uint32_t* __restrict__ tabS,    // packed bf16x2 per entry
    const uint32_t* __restrict__ tabT,
    const float* __restrict__ one_m,
    f2v* __restrict__ ws, int N, int half_grid)
{
    int blk = blockIdx.x;
    int hi = (blk >= half_grid) ? 1 : 0;
    int blkp = blk - hi * half_grid;
    int l = (blkp & 7) + hi * 8;                 // XCD k <- levels k, k+8
    int n = ((blkp >> 3) << 8) + threadIdx.x;    // 256 points per block
    if (n >= N) return;

    int r = c_res[l];
    uint32_t ru = (uint32_t)r;
    float rf1 = (float)r - 1.0f;
    const bool dirS = (l <= 8), dirT = (l <= 2);
    const uint32_t* tlS = tabS + ((size_t)l << 19);
    const uint32_t* tlT = tabT + ((size_t)l << 19);

    f4v xv = __builtin_nontemporal_load((const f4v*)x + n);

    float p0 = xv.x * rf1, p1 = xv.y * rf1, p2 = xv.z * rf1, p3 = xv.w * rf1;
    float f0 = floorf(p0), f1 = floorf(p1), f2 = floorf(p2), f3 = floorf(p3);
    float w0 = p0 - f0, w1 = p1 - f1, w2 = p2 - f2, w3 = p3 - f3;
    uint32_t c0a = (uint32_t)f0;   // c0a+1 may exceed r-1 only when w0==0 (weight 0)

    // ---- issue ALL T loads (pair + predicated odd per corner-pair) -------
    u2v pvT[8];
    uint32_t ovT[8];
    uint32_t swT = 0u, nbT = 0u;
    #pragma unroll
    for (int pi = 0; pi < 8; ++pi) {
        float o1 = (float)(pi & 1);
        float o2 = (float)((pi >> 1) & 1);
        float o3 = (float)((pi >> 2) & 1);
        uint32_t c1 = (uint32_t)fminf(f1 + o1, rf1);
        uint32_t c2 = (uint32_t)fminf(f2 + o2, rf1);
        uint32_t c3 = (uint32_t)fminf(f3 + o3, rf1);
        uint32_t ia, ib, needi;
        if (dirT) {
            uint32_t base = ru * (c1 + ru * (c2 + ru * c3));
            ia = base + c0a;
            ib = ia + 1;
            needi = ia & 1u;          // even -> pair covers both
        } else {
            uint32_t hh = (c1 * 2654435761u) ^ (c2 * 805459861u)
                        ^ (c3 * 3674653429u);
            ia = (c0a ^ hh) & TMASK;
            ib = ((c0a + 1u) ^ hh) & TMASK;
            needi = c0a & 1u;         // even c0a -> idxb == idxa^1, in pair
        }
        pvT[pi] = *(const u2v*)(tlT + (ia & ~1u));
        if (needi) ovT[pi] = tlT[ib];
        swT |= (ia & 1u) << pi;
        nbT |= needi << pi;
    }

    // ---- issue ALL S loads -----------------------------------------------
    u2v pvS[4];
    uint32_t ovS[4];
    uint32_t swS = 0u, nbS = 0u;
    #pragma unroll
    for (int pi = 0; pi < 4; ++pi) {
        float o1 = (float)(pi & 1);
        float o2 = (float)((pi >> 1) & 1);
        uint32_t c1 = (uint32_t)fminf(f1 + o1, rf1);
        uint32_t c2 = (uint32_t)fminf(f2 + o2, rf1);
        uint32_t ia, ib, needi;
        if (dirS) {
            uint32_t base = ru * (c1 + ru * c2);
            ia = base + c0a;
            ib = ia + 1;
            needi = ia & 1u;
        } else {
            uint32_t hh = (c1 * 2654435761u) ^ (c2 * 805459861u);
            ia = (c0a ^ hh) & TMASK;
            ib = ((c0a + 1u) ^ hh) & TMASK;
            needi = c0a & 1u;
        }
        pvS[pi] = *(const u2v*)(tlS + (ia & ~1u));
        if (needi) ovS[pi] = tlS[ib];
        swS |= (ia & 1u) << pi;
        nbS |= needi << pi;
    }

    // ---- one_m load (coalesced, last in the vmcnt queue) -----------------
    float om = __builtin_nontemporal_load(one_m + n);

    // ---- accumulate: T (while S may still be in flight), then S ----------
    float t0 = 0.0f, t1 = 0.0f;
    float wva = 1.0f - w0, wvb = w0;
    #pragma unroll
    for (int pi = 0; pi < 8; ++pi) {
        float bw = ((pi & 1) ? w1 : 1.0f - w1)
                 * (((pi >> 1) & 1) ? w2 : 1.0f - w2)
                 * (((pi >> 2) & 1) ? w3 : 1.0f - w3);
        uint32_t sw = (swT >> pi) & 1u;
        uint32_t ea = sw ? pvT[pi].y : pvT[pi].x;
        uint32_t eb = sw ? pvT[pi].x : pvT[pi].y;
        if ((nbT >> pi) & 1u) eb = ovT[pi];
        float wa = bw * wva, wb = bw * wvb;
        t0 += wa * bf_lo(ea) + wb * bf_lo(eb);
        t1 += wa * bf_hi(ea) + wb * bf_hi(eb);
    }
    float s0 = 0.0f, s1 = 0.0f;
    #pragma unroll
    for (int pi = 0; pi < 4; ++pi) {
        float bw = ((pi & 1) ? w1 : 1.0f - w1)
                 * (((pi >> 1) & 1) ? w2 : 1.0f - w2);
        uint32_t sw = (swS >> pi) & 1u;
        uint32_t ea = sw ? pvS[pi].y : pvS[pi].x;
        uint32_t eb = sw ? pvS[pi].x : pvS[pi].y;
        if ((nbS >> pi) & 1u) eb = ovS[pi];
        float wa = bw * wva, wb = bw * wvb;
        s0 += wa * bf_lo(ea) + wb * bf_lo(eb);
        s1 += wa * bf_hi(ea) + wb * bf_hi(eb);
    }

    f2v outv;
    outv.x = s0 + t0 * om;
    outv.y = s1 + t1 * om;
    __builtin_nontemporal_store(outv, ws + (size_t)l * N + n);
}

// ---- K3: transpose ws (level-major) -> out (point-major) -----------------
__global__ __launch_bounds__(256) void out_kernel(
    const f2v* __restrict__ ws, f4v* __restrict__ out4, int N)
{
    __shared__ float lds[256 * 33];
    int tid = threadIdx.x;
    int n = (blockIdx.x << 8) + tid;

    if (n < N) {
        #pragma unroll
        for (int l = 0; l < NLEV; ++l) {
            f2v v = __builtin_nontemporal_load(ws + (size_t)l * N + n);
            lds[tid * 33 + 2 * l]     = v.x;
            lds[tid * 33 + 2 * l + 1] = v.y;
        }
    }
    __syncthreads();

    size_t out4base = (size_t)blockIdx.x * 2048;
    size_t limit = (size_t)N * 8;
    #pragma unroll
    for (int k = 0; k < 8; ++k) {
        int g = k * 256 + tid;
        size_t G = out4base + g;
        if (G < limit) {
            int p = g >> 3;
            int e = (g & 7) * 4;
            f4v v;
            v.x = lds[p * 33 + e];
            v.y = lds[p * 33 + e + 1];
            v.z = lds[p * 33 + e + 2];
            v.w = lds[p * 33 + e + 3];
            __builtin_nontemporal_store(v, out4 + G);
        }
    }
}

// ---- fallback: monolithic (tiny ws) --------------------------------------
__global__ __launch_bounds__(256) void grid_enc_kernel(
    const float* __restrict__ x,
    const float* __restrict__ tab_s,
    const float* __restrict__ tab_t,
    const float* __restrict__ tab_m,
    float* __restrict__ out, int N)
{
    int tid = blockIdx.x * blockDim.x + threadIdx.x;
    if (tid >= N * NLEV) return;
    int n = tid >> 4, l = tid & 15;
    float x0 = x[n*4+0], x1 = x[n*4+1], x2 = x[n*4+2], x3 = x[n*4+3];
    float one_m;
    {
        float q0 = fminf(fmaxf(rintf(x0*127.0f),0.0f),127.0f);
        float q1 = fminf(fmaxf(rintf(x1*127.0f),0.0f),127.0f);
        float q2 = fminf(fmaxf(rintf(x2*127.0f),0.0f),127.0f);
        uint32_t idx = (uint32_t)q0 + ((uint32_t)q1<<7) + ((uint32_t)q2<<14);
        one_m = 1.0f - 1.0f/(1.0f + expf(-tab_m[idx]));
    }
    int r = c_res[l]; uint32_t ru = (uint32_t)r; float rf1 = (float)r - 1.0f;
    float p0 = x0*rf1, p1 = x1*rf1, p2 = x2*rf1, p3 = x3*rf1;
    float f0 = floorf(p0), f1 = floorf(p1), f2 = floorf(p2), f3 = floorf(p3);
    float w0 = p0-f0, w1 = p1-f1, w2 = p2-f2, w3 = p3-f3;
    const float2* ts2 = (const float2*)tab_s + ((size_t)l<<19);
    const float2* tt2 = (const float2*)tab_t + ((size_t)l<<19);
    const bool sd = (l<=8), td = (l<=2);
    float s0=0,s1=0;
    #pragma unroll
    for (int c = 0; c < 8; ++c) {
        uint32_t c0 = (uint32_t)fminf(f0+(float)(c&1), rf1);
        uint32_t c1 = (uint32_t)fminf(f1+(float)((c>>1)&1), rf1);
        uint32_t c2 = (uint32_t)fminf(f2+(float)((c>>2)&1), rf1);
        float wt = ((c&1)?w0:1.0f-w0)*(((c>>1)&1)?w1:1.0f-w1)*(((c>>2)&1)?w2:1.0f-w2);
        uint32_t idx = sd ? (c0 + c1*ru + c2*ru*ru)
                          : (c0 ^ (c1*2654435761u) ^ (c2*805459861u));
        float2 e = ts2[idx & TMASK]; s0 += wt*e.x; s1 += wt*e.y;
    }
    float t0=0,t1=0;
    #pragma unroll
    for (int c = 0; c < 16; ++c) {
        uint32_t c0 = (uint32_t)fminf(f0+(float)(c&1), rf1);
        uint32_t c1 = (uint32_t)fminf(f1+(float)((c>>1)&1), rf1);
        uint32_t c2 = (uint32_t)fminf(f2+(float)((c>>2)&1), rf1);
        uint32_t c3 = (uint32_t)fminf(f3+(float)((c>>3)&1), rf1);
        float wt = ((c&1)?w0:1.0f-w0)*(((c>>1)&1)?w1:1.0f-w1)
                 *(((c>>2)&1)?w2:1.0f-w2)*(((c>>3)&1)?w3:1.0f-w3);
        uint32_t idx = td ? (c0 + ru*(c1 + ru*(c2 + ru*c3)))
                          : (c0 ^ (c1*2654435761u) ^ (c2*805459861u) ^ (c3*3674653429u));
        float2 e = tt2[idx & TMASK]; t0 += wt*e.x; t1 += wt*e.y;
    }
    size_t o = (size_t)n*32 + 2*(size_t)l;
    out[o] = s0 + t0*one_m; out[o+1] = s1 + t1*one_m;
}

extern "C" void kernel_launch(void* const* d_in, const int* in_sizes, int n_in,
                              void* d_out, int out_size, void* d_ws, size_t ws_size,
                              hipStream_t stream) {
    const float* x     = (const float*)d_in[0];
    const float* tab_s = (const float*)d_in[1];
    const float* tab_t = (const float*)d_in[2];
    const float* tab_m = (const float*)d_in[3];
    float* out = (float*)d_out;

    int N = in_sizes[0] / 4;                            // 400000
    size_t wm_b = (((size_t)N * 4) + 255) & ~(size_t)255;
    size_t wc_b = (size_t)N * NLEV * 8;                 // 51.2 MB
    size_t tb_b = (size_t)NLEV * (1u << 19) * 4;        // 33.55 MB per packed table
    int nchunk = (N + 255) / 256;

    if (ws_size >= wm_b + wc_b + 2 * tb_b) {
        float* wm = (float*)d_ws;
        f2v*   wc = (f2v*)((char*)d_ws + wm_b);
        uint32_t* ps = (uint32_t*)((char*)d_ws + wm_b + wc_b);
        uint32_t* pt = ps + (size_t)NLEV * (1u << 19);
        int half = NLEV * (1 << 19) / 2;                // f4 count per table
        int half_grid = 8 * nchunk;
        conv_kernel<<<(2 * half + 255) / 256, 256, 0, stream>>>(
            (const f4v*)tab_s, (const f4v*)tab_t, (u2v*)ps, (u2v*)pt, half);
        m_kernel<<<nchunk, 256, 0, stream>>>(x, tab_m, wm, N);
        enc_fused<<<16 * nchunk, 256, 0, stream>>>(x, ps, pt, wm, wc, N, half_grid);
        out_kernel<<<nchunk, 256, 0, stream>>>(wc, (f4v*)out, N);
    } else {
        int total = N * NLEV;
        grid_enc_kernel<<<(total + 255) / 256, 256, 0, stream>>>(x, tab_s, tab_t, tab_m, out, N);
    }
}

// Round 7
// 595.056 us; speedup vs baseline: 1.4112x; 1.4112x over previous
//
#include <hip/hip_runtime.h>
#include <cstdint>

#define NLEV 16
#define TMASK ((1u << 19) - 1u)

typedef float f4v __attribute__((ext_vector_type(4)));
typedef float f2v __attribute__((ext_vector_type(2)));
typedef uint32_t u2v __attribute__((ext_vector_type(2)));

// res[l] = ceil(16 * 1.2^l) in float64 (matches numpy)
__constant__ int c_res[NLEV] = {16, 20, 24, 28, 34, 40, 48, 58, 69, 83,
                                100, 119, 143, 172, 206, 247};

__device__ __forceinline__ float bf_lo(uint32_t e) { return __uint_as_float(e << 16); }
__device__ __forceinline__ float bf_hi(uint32_t e) { return __uint_as_float(e & 0xFFFF0000u); }
__device__ __forceinline__ uint32_t rne16(float f) {
    uint32_t u = __float_as_uint(f);
    return (u + 0x7fffu + ((u >> 16) & 1u)) >> 16;
}

// ---- K-1: pack fp32 float2 entries -> one dword (2 x bf16, RNE) ----------
__global__ __launch_bounds__(256) void conv_kernel(
    const f4v* __restrict__ src_s, const f4v* __restrict__ src_t,
    u2v* __restrict__ dst_s, u2v* __restrict__ dst_t, int half)
{
    int i = blockIdx.x * 256 + threadIdx.x;           // one f4 = 2 entries
    const f4v* src = (i < half) ? src_s : src_t;
    u2v* dst = (i < half) ? dst_s : dst_t;
    int j = (i < half) ? i : i - half;
    if (j < half) {
        f4v v = __builtin_nontemporal_load(src + j);
        u2v o;
        o.x = rne16(v.x) | (rne16(v.y) << 16);
        o.y = rne16(v.z) | (rne16(v.w) << 16);
        __builtin_nontemporal_store(o, dst + j);
    }
}

// ---- K0: per-point  one_m = 1 - sigmoid(table_m[nearest]) ----------------
__global__ __launch_bounds__(256) void m_kernel(
    const float* __restrict__ x, const float* __restrict__ tab_m,
    float* __restrict__ one_m, int N)
{
    int n = blockIdx.x * 256 + threadIdx.x;
    if (n >= N) return;
    f4v xv = __builtin_nontemporal_load((const f4v*)x + n);
    float q0 = fminf(fmaxf(rintf(xv.x * 127.0f), 0.0f), 127.0f);
    float q1 = fminf(fmaxf(rintf(xv.y * 127.0f), 0.0f), 127.0f);
    float q2 = fminf(fmaxf(rintf(xv.z * 127.0f), 0.0f), 127.0f);
    uint32_t idx = (uint32_t)q0 + ((uint32_t)q1 << 7) + ((uint32_t)q2 << 14);
    float v = tab_m[idx];
    float m = 1.0f / (1.0f + expf(-v));
    __builtin_nontemporal_store(1.0f - m, one_m + n);
}

// ---- K1: FUSED S+T pass, ONE point per thread, XCD-balanced levels. ------
// Round-5 config (lb 256,6; VGPR 40) is the session best: enc 420us @60% occ.
// Round-6 (lb 256,8) spilled to scratch (VGPR 32, WRITE 674MB) -- reverted.
// This round's single change: level->XCD pairing (k, k+8) -> (k, 15-k).
// Level cost rises with l (coarse = tiny/L1/direct; fine = 2MB hashed/L2),
// so (k,k+8) made XCD0 light and XCD7 heavy; light XCDs drained their
// private block queues early and idled (observed occ 60% < 75% cap).
// Complementary pairing equalizes per-XCD work; L2 footprint per XCD stays
// exactly 2 levels x 2 tables = 4MB.
__global__ __launch_bounds__(256, 6) void enc_fused(
    const float* __restrict__ x,
    const uint32_t* __restrict__ tabS,    // packed bf16x2 per entry
    const uint32_t* __restrict__ tabT,
    const float* __restrict__ one_m,
    f2v* __restrict__ ws, int N, int half_grid)
{
    int blk = blockIdx.x;
    int hi = (blk >= half_grid) ? 1 : 0;
    int blkp = blk - hi * half_grid;
    int l = hi ? (15 - (blkp & 7)) : (blkp & 7);  // XCD k <- levels k, 15-k
    int n = ((blkp >> 3) << 8) + threadIdx.x;     // 256 points per block
    if (n >= N) return;

    int r = c_res[l];
    uint32_t ru = (uint32_t)r;
    float rf1 = (float)r - 1.0f;
    const bool dirS = (l <= 8), dirT = (l <= 2);
    const uint32_t* tlS = tabS + ((size_t)l << 19);
    const uint32_t* tlT = tabT + ((size_t)l << 19);

    f4v xv = __builtin_nontemporal_load((const f4v*)x + n);

    float p0 = xv.x * rf1, p1 = xv.y * rf1, p2 = xv.z * rf1, p3 = xv.w * rf1;
    float f0 = floorf(p0), f1 = floorf(p1), f2 = floorf(p2), f3 = floorf(p3);
    float w0 = p0 - f0, w1 = p1 - f1, w2 = p2 - f2, w3 = p3 - f3;
    uint32_t c0a = (uint32_t)f0;   // c0a+1 may exceed r-1 only when w0==0 (weight 0)

    // ---- issue ALL T loads (pair + predicated odd per corner-pair) -------
    u2v pvT[8];
    uint32_t ovT[8];
    uint32_t swT = 0u, nbT = 0u;
    #pragma unroll
    for (int pi = 0; pi < 8; ++pi) {
        float o1 = (float)(pi & 1);
        float o2 = (float)((pi >> 1) & 1);
        float o3 = (float)((pi >> 2) & 1);
        uint32_t c1 = (uint32_t)fminf(f1 + o1, rf1);
        uint32_t c2 = (uint32_t)fminf(f2 + o2, rf1);
        uint32_t c3 = (uint32_t)fminf(f3 + o3, rf1);
        uint32_t ia, ib, needi;
        if (dirT) {
            uint32_t base = ru * (c1 + ru * (c2 + ru * c3));
            ia = base + c0a;
            ib = ia + 1;
            needi = ia & 1u;          // even -> pair covers both
        } else {
            uint32_t hh = (c1 * 2654435761u) ^ (c2 * 805459861u)
                        ^ (c3 * 3674653429u);
            ia = (c0a ^ hh) & TMASK;
            ib = ((c0a + 1u) ^ hh) & TMASK;
            needi = c0a & 1u;         // even c0a -> idxb == idxa^1, in pair
        }
        pvT[pi] = *(const u2v*)(tlT + (ia & ~1u));
        if (needi) ovT[pi] = tlT[ib];
        swT |= (ia & 1u) << pi;
        nbT |= needi << pi;
    }

    // ---- issue ALL S loads -----------------------------------------------
    u2v pvS[4];
    uint32_t ovS[4];
    uint32_t swS = 0u, nbS = 0u;
    #pragma unroll
    for (int pi = 0; pi < 4; ++pi) {
        float o1 = (float)(pi & 1);
        float o2 = (float)((pi >> 1) & 1);
        uint32_t c1 = (uint32_t)fminf(f1 + o1, rf1);
        uint32_t c2 = (uint32_t)fminf(f2 + o2, rf1);
        uint32_t ia, ib, needi;
        if (dirS) {
            uint32_t base = ru * (c1 + ru * c2);
            ia = base + c0a;
            ib = ia + 1;
            needi = ia & 1u;
        } else {
            uint32_t hh = (c1 * 2654435761u) ^ (c2 * 805459861u);
            ia = (c0a ^ hh) & TMASK;
            ib = ((c0a + 1u) ^ hh) & TMASK;
            needi = c0a & 1u;
        }
        pvS[pi] = *(const u2v*)(tlS + (ia & ~1u));
        if (needi) ovS[pi] = tlS[ib];
        swS |= (ia & 1u) << pi;
        nbS |= needi << pi;
    }

    // ---- one_m load (coalesced, last in the vmcnt queue) -----------------
    float om = __builtin_nontemporal_load(one_m + n);

    // ---- accumulate: T (while S may still be in flight), then S ----------
    float t0 = 0.0f, t1 = 0.0f;
    float wva = 1.0f - w0, wvb = w0;
    #pragma unroll
    for (int pi = 0; pi < 8; ++pi) {
        float bw = ((pi & 1) ? w1 : 1.0f - w1)
                 * (((pi >> 1) & 1) ? w2 : 1.0f - w2)
                 * (((pi >> 2) & 1) ? w3 : 1.0f - w3);
        uint32_t sw = (swT >> pi) & 1u;
        uint32_t ea = sw ? pvT[pi].y : pvT[pi].x;
        uint32_t eb = sw ? pvT[pi].x : pvT[pi].y;
        if ((nbT >> pi) & 1u) eb = ovT[pi];
        float wa = bw * wva, wb = bw * wvb;
        t0 += wa * bf_lo(ea) + wb * bf_lo(eb);
        t1 += wa * bf_hi(ea) + wb * bf_hi(eb);
    }
    float s0 = 0.0f, s1 = 0.0f;
    #pragma unroll
    for (int pi = 0; pi < 4; ++pi) {
        float bw = ((pi & 1) ? w1 : 1.0f - w1)
                 * (((pi >> 1) & 1) ? w2 : 1.0f - w2);
        uint32_t sw = (swS >> pi) & 1u;
        uint32_t ea = sw ? pvS[pi].y : pvS[pi].x;
        uint32_t eb = sw ? pvS[pi].x : pvS[pi].y;
        if ((nbS >> pi) & 1u) eb = ovS[pi];
        float wa = bw * wva, wb = bw * wvb;
        s0 += wa * bf_lo(ea) + wb * bf_lo(eb);
        s1 += wa * bf_hi(ea) + wb * bf_hi(eb);
    }

    f2v outv;
    outv.x = s0 + t0 * om;
    outv.y = s1 + t1 * om;
    __builtin_nontemporal_store(outv, ws + (size_t)l * N + n);
}

// ---- K3: transpose ws (level-major) -> out (point-major) -----------------
__global__ __launch_bounds__(256) void out_kernel(
    const f2v* __restrict__ ws, f4v* __restrict__ out4, int N)
{
    __shared__ float lds[256 * 33];
    int tid = threadIdx.x;
    int n = (blockIdx.x << 8) + tid;

    if (n < N) {
        #pragma unroll
        for (int l = 0; l < NLEV; ++l) {
            f2v v = __builtin_nontemporal_load(ws + (size_t)l * N + n);
            lds[tid * 33 + 2 * l]     = v.x;
            lds[tid * 33 + 2 * l + 1] = v.y;
        }
    }
    __syncthreads();

    size_t out4base = (size_t)blockIdx.x * 2048;
    size_t limit = (size_t)N * 8;
    #pragma unroll
    for (int k = 0; k < 8; ++k) {
        int g = k * 256 + tid;
        size_t G = out4base + g;
        if (G < limit) {
            int p = g >> 3;
            int e = (g & 7) * 4;
            f4v v;
            v.x = lds[p * 33 + e];
            v.y = lds[p * 33 + e + 1];
            v.z = lds[p * 33 + e + 2];
            v.w = lds[p * 33 + e + 3];
            __builtin_nontemporal_store(v, out4 + G);
        }
    }
}

// ---- fallback: monolithic (tiny ws) --------------------------------------
__global__ __launch_bounds__(256) void grid_enc_kernel(
    const float* __restrict__ x,
    const float* __restrict__ tab_s,
    const float* __restrict__ tab_t,
    const float* __restrict__ tab_m,
    float* __restrict__ out, int N)
{
    int tid = blockIdx.x * blockDim.x + threadIdx.x;
    if (tid >= N * NLEV) return;
    int n = tid >> 4, l = tid & 15;
    float x0 = x[n*4+0], x1 = x[n*4+1], x2 = x[n*4+2], x3 = x[n*4+3];
    float one_m;
    {
        float q0 = fminf(fmaxf(rintf(x0*127.0f),0.0f),127.0f);
        float q1 = fminf(fmaxf(rintf(x1*127.0f),0.0f),127.0f);
        float q2 = fminf(fmaxf(rintf(x2*127.0f),0.0f),127.0f);
        uint32_t idx = (uint32_t)q0 + ((uint32_t)q1<<7) + ((uint32_t)q2<<14);
        one_m = 1.0f - 1.0f/(1.0f + expf(-tab_m[idx]));
    }
    int r = c_res[l]; uint32_t ru = (uint32_t)r; float rf1 = (float)r - 1.0f;
    float p0 = x0*rf1, p1 = x1*rf1, p2 = x2*rf1, p3 = x3*rf1;
    float f0 = floorf(p0), f1 = floorf(p1), f2 = floorf(p2), f3 = floorf(p3);
    float w0 = p0-f0, w1 = p1-f1, w2 = p2-f2, w3 = p3-f3;
    const float2* ts2 = (const float2*)tab_s + ((size_t)l<<19);
    const float2* tt2 = (const float2*)tab_t + ((size_t)l<<19);
    const bool sd = (l<=8), td = (l<=2);
    float s0=0,s1=0;
    #pragma unroll
    for (int c = 0; c < 8; ++c) {
        uint32_t c0 = (uint32_t)fminf(f0+(float)(c&1), rf1);
        uint32_t c1 = (uint32_t)fminf(f1+(float)((c>>1)&1), rf1);
        uint32_t c2 = (uint32_t)fminf(f2+(float)((c>>2)&1), rf1);
        float wt = ((c&1)?w0:1.0f-w0)*(((c>>1)&1)?w1:1.0f-w1)*(((c>>2)&1)?w2:1.0f-w2);
        uint32_t idx = sd ? (c0 + c1*ru + c2*ru*ru)
                          : (c0 ^ (c1*2654435761u) ^ (c2*805459861u));
        float2 e = ts2[idx & TMASK]; s0 += wt*e.x; s1 += wt*e.y;
    }
    float t0=0,t1=0;
    #pragma unroll
    for (int c = 0; c < 16; ++c) {
        uint32_t c0 = (uint32_t)fminf(f0+(float)(c&1), rf1);
        uint32_t c1 = (uint32_t)fminf(f1+(float)((c>>1)&1), rf1);
        uint32_t c2 = (uint32_t)fminf(f2+(float)((c>>2)&1), rf1);
        uint32_t c3 = (uint32_t)fminf(f3+(float)((c>>3)&1), rf1);
        float wt = ((c&1)?w0:1.0f-w0)*(((c>>1)&1)?w1:1.0f-w1)
                 *(((c>>2)&1)?w2:1.0f-w2)*(((c>>3)&1)?w3:1.0f-w3);
        uint32_t idx = td ? (c0 + ru*(c1 + ru*(c2 + ru*c3)))
                          : (c0 ^ (c1*2654435761u) ^ (c2*805459861u) ^ (c3*3674653429u));
        float2 e = tt2[idx & TMASK]; t0 += wt*e.x; t1 += wt*e.y;
    }
    size_t o = (size_t)n*32 + 2*(size_t)l;
    out[o] = s0 + t0*one_m; out[o+1] = s1 + t1*one_m;
}

extern "C" void kernel_launch(void* const* d_in, const int* in_sizes, int n_in,
                              void* d_out, int out_size, void* d_ws, size_t ws_size,
                              hipStream_t stream) {
    const float* x     = (const float*)d_in[0];
    const float* tab_s = (const float*)d_in[1];
    const float* tab_t = (const float*)d_in[2];
    const float* tab_m = (const float*)d_in[3];
    float* out = (float*)d_out;

    int N = in_sizes[0] / 4;                            // 400000
    size_t wm_b = (((size_t)N * 4) + 255) & ~(size_t)255;
    size_t wc_b = (size_t)N * NLEV * 8;                 // 51.2 MB
    size_t tb_b = (size_t)NLEV * (1u << 19) * 4;        // 33.55 MB per packed table
    int nchunk = (N + 255) / 256;

    if (ws_size >= wm_b + wc_b + 2 * tb_b) {
        float* wm = (float*)d_ws;
        f2v*   wc = (f2v*)((char*)d_ws + wm_b);
        uint32_t* ps = (uint32_t*)((char*)d_ws + wm_b + wc_b);
        uint32_t* pt = ps + (size_t)NLEV * (1u << 19);
        int half = NLEV * (1 << 19) / 2;                // f4 count per table
        int half_grid = 8 * nchunk;
        conv_kernel<<<(2 * half + 255) / 256, 256, 0, stream>>>(
            (const f4v*)tab_s, (const f4v*)tab_t, (u2v*)ps, (u2v*)pt, half);
        m_kernel<<<nchunk, 256, 0, stream>>>(x, tab_m, wm, N);
        enc_fused<<<16 * nchunk, 256, 0, stream>>>(x, ps, pt, wm, wc, N, half_grid);
        out_kernel<<<nchunk, 256, 0, stream>>>(wc, (f4v*)out, N);
    } else {
        int total = N * NLEV;
        grid_enc_kernel<<<(total + 255) / 256, 256, 0, stream>>>(x, tab_s, tab_t, tab_m, out, N);
    }
}